// Round 2
// baseline (344.412 us; speedup 1.0000x reference)
//
#include <hip/hip_runtime.h>
#include <math.h>

// Problem constants (from reference)
#define B_ 16
#define T_ 4096
#define C_ 512
#define E_ 64
#define K_ 2048
#define N_ (B_*T_)          // 65536
#define ZQ_ELEMS 4194304    // B*E*T

typedef __attribute__((ext_vector_type(8))) short short8;
typedef __attribute__((ext_vector_type(4))) short short4v;
typedef __attribute__((ext_vector_type(4))) float f32x4;

// ws layout (bytes):
//   ehi_sw : [16][8192] bf16 B-frag-tiled codebook hi @ 0       (256 KB)
//   elo_sw : lo plane                              @ 262144     (256 KB)
//   nhcc   : [K] f32 (-0.5*||e_k||^2)              @ 524288     (8 KB)
//   w_hi   : [64][512] bf16                        @ 532480     (64 KB)
//   w_lo   : [64][512] bf16                        @ 598016     (64 KB)
//   hist   : [K] i32                               @ 663552     (8 KB)  <- memset w/ loss
//   loss   : f32                                   @ 671744     (4 B)
//   himg   : [512 groups][16384] shorts (hi 8192 | lo 8192) @ 1 MB (16.78 MB)
#define WS_EHI   0
#define WS_ELO   262144
#define WS_NHCC  524288
#define WS_WHI   532480
#define WS_WLO   598016
#define WS_HIST  663552
#define WS_LOSS  671744
#define WS_HIMG  1048576
#define WS_NEED  (WS_HIMG + 512*16384*2)   // ~17.8 MB

struct HiLo { short hi, lo; };

__device__ __forceinline__ unsigned short rne16(float v) {
    unsigned u = __float_as_uint(v);
    return (unsigned short)((u + 0x7FFFu + ((u >> 16) & 1u)) >> 16);
}
__device__ __forceinline__ HiLo split_rne(float v) {
    HiLo r;
    unsigned hb = rne16(v);
    r.hi = (short)hb;
    float hf = __uint_as_float((unsigned)hb << 16);
    r.lo = (short)rne16(v - hf);
    return r;
}

// Async global->LDS, 16B per lane. Dest must be wave-uniform base + lane*16
// (all call sites: per-lane dest linear in tid).
typedef const __attribute__((address_space(1))) void* gas1_t;
typedef __attribute__((address_space(3))) void* las3_t;
__device__ __forceinline__ void gl16(const void* g, void* l) {
    __builtin_amdgcn_global_load_lds((gas1_t)g, (las3_t)l, 16, 0, 0);
}

// ---------------------------------------------------------------------------
// Prep. Blocks 0..63: embed -> B-frag-tiled bf16 hi/lo + nhcc.
//       Blocks 64..95: W -> flat bf16 hi/lo.
// Tiled layout per 128-k chunk (8192 shorts/plane): slot for (r=k&127, e):
//   kt=r>>4, col=r&15, ks=e>>5, qe=(e>>3)&3 -> ((kt*2+ks)*64 + qe*16 + col)*8 + (e&7)
// so vq staging is a linear copy (global_load_lds) and all scan ds_read_b128
// are lane-linear.
// ---------------------------------------------------------------------------
__global__ void prep_kernel(const float* __restrict__ embed,
                            const float* __restrict__ W,
                            short* __restrict__ ehi, short* __restrict__ elo,
                            float* __restrict__ nhcc,
                            short* __restrict__ whi, short* __restrict__ wlo) {
    const int tid = threadIdx.x;
    if (blockIdx.x < 64) {
        const int row = blockIdx.x * 32 + (tid >> 3);
        const int g = tid & 7;
        const float* src = embed + (size_t)row * 64 + g * 8;
        short8 hv, lv;
        float s = 0.f;
#pragma unroll
        for (int j = 0; j < 8; ++j) {
            float v = src[j];
            s = fmaf(v, v, s);
            HiLo r = split_rne(v);
            hv[j] = r.hi; lv[j] = r.lo;
        }
        const int c128 = row >> 7, r = row & 127;
        const int kt = r >> 4, col = r & 15, ks = g >> 2, qe = g & 3;
        const int slot = (kt * 2 + ks) * 64 + qe * 16 + col;
        *(short8*)(ehi + c128 * 8192 + slot * 8) = hv;
        *(short8*)(elo + c128 * 8192 + slot * 8) = lv;
        s += __shfl_xor(s, 1, 64);
        s += __shfl_xor(s, 2, 64);
        s += __shfl_xor(s, 4, 64);
        if (g == 0) nhcc[row] = -0.5f * s;
    } else {
        int idx = ((blockIdx.x - 64) * 256 + tid) * 4;
        float4 v = *(const float4*)(W + idx);
        short4v h, l;
        HiLo a = split_rne(v.x); h[0] = a.hi; l[0] = a.lo;
        HiLo b = split_rne(v.y); h[1] = b.hi; l[1] = b.lo;
        HiLo c = split_rne(v.z); h[2] = c.hi; l[2] = c.lo;
        HiLo d = split_rne(v.w); h[3] = d.hi; l[3] = d.lo;
        *(short4v*)(whi + idx) = h;
        *(short4v*)(wlo + idx) = l;
    }
}

// ---------------------------------------------------------------------------
// proj_kernel: h = W.x + bias for a 64-t tile; writes bf16 hi/lo h-image in
// A-frag order to himg (so vq loads fragments lane-linear from global).
// Block 256 thr (4 waves, one 16-t tile each). Grid 1024 (= B * T/64).
// LDS 16 KB dbuf -> up to 4 blocks/CU; x staged via global_load_lds.
// x tile XOR-deswizzled (t ^= 16 for odd c>>3) -> 2-way LDS reads (free).
// ---------------------------------------------------------------------------
__global__ __launch_bounds__(256, 4) void proj_kernel(
        const float* __restrict__ x,
        const short* __restrict__ whi, const short* __restrict__ wlo,
        const float* __restrict__ bias,
        short* __restrict__ himg, float* __restrict__ lossacc) {
    __shared__ __align__(16) float xsf[2][2048];   // [2][32c][64t]

    const int tid = threadIdx.x;
    const int wave = tid >> 6, lane = tid & 63;
    const int row16 = lane & 15, quad = lane >> 4;
    const int blk = blockIdx.x;
    const int b  = blk >> 6;
    const int t0 = (blk & 63) * 64;
    const float* xb = x + (size_t)b * C_ * T_ + t0;

    f32x4 acc[4];
#pragma unroll
    for (int et = 0; et < 4; ++et) acc[et] = (f32x4){0.f, 0.f, 0.f, 0.f};

    // stage c-chunk 0 (8 KB): o = j*256+tid; row c=o>>4, 16B piece (o&15);
    // source t pre-swizzled so LDS stays linear but content is deswizzled.
#pragma unroll
    for (int j = 0; j < 2; ++j) {
        int o = j * 256 + tid;
        int tsrc = ((o & 15) * 4) ^ (((o >> 7) & 1) << 4);
        gl16(xb + (size_t)(o >> 4) * T_ + tsrc, &xsf[0][o * 4]);
    }
    __syncthreads();

    for (int it = 0; it < 16; ++it) {
        const int c0 = it * 32;
        const int p = it & 1;
        if (it < 15) {
#pragma unroll
            for (int j = 0; j < 2; ++j) {
                int o = j * 256 + tid;
                int tsrc = ((o & 15) * 4) ^ (((o >> 7) & 1) << 4);
                gl16(xb + (size_t)(c0 + 32 + (o >> 4)) * T_ + tsrc,
                     &xsf[p ^ 1][o * 4]);
            }
        }
        const float* xsb = xsf[p];
        const int tsw = (wave * 16 + row16) ^ ((quad & 1) << 4);
        short8 bh, bl;
#pragma unroll
        for (int j = 0; j < 8; ++j) {
            float v = xsb[(quad * 8 + j) * 64 + tsw];
            HiLo r = split_rne(v);
            bh[j] = r.hi; bl[j] = r.lo;
        }
#pragma unroll
        for (int et = 0; et < 4; ++et) {
            size_t aoff = (size_t)(et * 16 + row16) * C_ + c0 + quad * 8;
            short8 ah = *(const short8*)(whi + aoff);
            short8 al = *(const short8*)(wlo + aoff);
            acc[et] = __builtin_amdgcn_mfma_f32_16x16x32_bf16(ah, bh, acc[et], 0, 0, 0);
            acc[et] = __builtin_amdgcn_mfma_f32_16x16x32_bf16(al, bh, acc[et], 0, 0, 0);
            acc[et] = __builtin_amdgcn_mfma_f32_16x16x32_bf16(ah, bl, acc[et], 0, 0, 0);
            acc[et] = __builtin_amdgcn_mfma_f32_16x16x32_bf16(al, bl, acc[et], 0, 0, 0);
        }
        __syncthreads();
    }

    // Epilogue: bias, ||h||^2, store h hi/lo in A-frag order to himg.
    // 128-row group g = blk>>1; this block's waves are w2 = (blk&1)*4 + wave.
    short* gb = himg + (size_t)(blk >> 1) * 16384;
    const int w2 = (blk & 1) * 4 + wave;
    float hh = 0.f;
#pragma unroll
    for (int et = 0; et < 4; ++et) {
        float4 bv = *(const float4*)(bias + et * 16 + quad * 4);
        f32x4 a = acc[et];
        a[0] += bv.x; a[1] += bv.y; a[2] += bv.z; a[3] += bv.w;
        hh = fmaf(a[0], a[0], hh); hh = fmaf(a[1], a[1], hh);
        hh = fmaf(a[2], a[2], hh); hh = fmaf(a[3], a[3], hh);
        short4v hv, lv;
#pragma unroll
        for (int r = 0; r < 4; ++r) {
            HiLo sp = split_rne(a[r]);
            hv[r] = sp.hi; lv[r] = sp.lo;
        }
        const int ks = et >> 1;
        const int qe = (et & 1) * 2 + (quad >> 1);
        const int j0 = (quad & 1) * 4;
        const int sl = ((w2 * 2 + ks) * 64 + qe * 16 + row16) * 8 + j0;
        *(short4v*)(gb + sl) = hv;
        *(short4v*)(gb + 8192 + sl) = lv;
    }
#pragma unroll
    for (int m = 1; m < 64; m <<= 1) hh += __shfl_xor(hh, m, 64);
    if (lane == 0) atomicAdd(lossacc, hh);
}

// ---------------------------------------------------------------------------
// vq_kernel: argmin over K=2048 codes + fused gather/transpose.
// Block 512 thr (8 waves) = one 128-row group. Grid 512.
// A-frags load lane-linear from himg (global, L2-hot) -> no aimg LDS pass.
// Codebook: global_load_lds dbuf, 16 chunks of 128 codes; kh-split waves.
// ---------------------------------------------------------------------------
__global__ __launch_bounds__(512, 4) void vq_kernel(
        const short* __restrict__ himg,
        const short* __restrict__ ehi, const short* __restrict__ elo,
        const float* __restrict__ nhcc,
        const float* __restrict__ embed, float* __restrict__ out,
        int* __restrict__ hist, float* __restrict__ lossacc) {
    __shared__ __align__(16) char smem[68096];
    short* es   = (short*)smem;             // [2][16384] shorts dbuf (64 KB)
    float* ccs  = (float*)(smem + 65536);   // [2][128] f32
    int*   qsm  = (int*)(smem + 66560);     // [128]
    float* vtmp = (float*)(smem + 67072);   // [128]
    int*   itmp = (int*)(smem + 67584);     // [128]
    float* tile = (float*)smem;             // phase 3: [128][69] f32 (35.3 KB)

    const int tid = threadIdx.x;
    const int wave = tid >> 6, lane = tid & 63;
    const int row16 = lane & 15, quad = lane >> 4;
    const int g = blockIdx.x;
    const int b  = g >> 5;
    const int t0 = (g & 31) * 128;

    f32x4 cc = *(const f32x4*)(nhcc + tid * 4);

    // A-frags: lane-linear from global h-image.
    const short* gb = himg + (size_t)g * 16384;
    const int pair = wave & 3, kh = wave >> 2;
    short8 a_hi[2][2], a_lo[2][2];
#pragma unroll
    for (int rt = 0; rt < 2; ++rt)
#pragma unroll
        for (int ks = 0; ks < 2; ++ks) {
            int sl = (((2 * pair + rt) * 2 + ks) * 64 + lane) * 8;
            a_hi[rt][ks] = *(const short8*)(gb + sl);
            a_lo[rt][ks] = *(const short8*)(gb + 8192 + sl);
        }

    // Stage codebook chunk 0 + ccs buf0.
#pragma unroll
    for (int j = 0; j < 2; ++j) {
        int o = (j * 512 + tid) * 8;
        gl16(ehi + o, es + o);
        gl16(elo + o, es + 8192 + o);
    }
    if ((tid >> 5) == 0) *(f32x4*)(ccs + (tid & 31) * 4) = cc;
    __syncthreads();

    float vmax[2][4];
    int   vidx[2][4];
#pragma unroll
    for (int rt = 0; rt < 2; ++rt)
#pragma unroll
        for (int rg = 0; rg < 4; ++rg) { vmax[rt][rg] = -3.4e38f; vidx[rt][rg] = 0; }

    for (int c = 0; c < 16; ++c) {
        if (c < 15) {
            const short* sh  = ehi + (c + 1) * 8192;
            const short* sl2 = elo + (c + 1) * 8192;
            short* dst = es + ((c + 1) & 1) * 16384;
#pragma unroll
            for (int j = 0; j < 2; ++j) {
                int o = (j * 512 + tid) * 8;
                gl16(sh + o, dst + o);
                gl16(sl2 + o, dst + 8192 + o);
            }
            if ((tid >> 5) == c + 1)
                *(f32x4*)(ccs + ((c + 1) & 1) * 128 + (tid & 31) * 4) = cc;
        }
        const short* eb = es + (c & 1) * 16384;
        const float* cb = ccs + (c & 1) * 128;
#pragma unroll
        for (int k4 = 0; k4 < 4; ++k4) {
            const int kt = kh * 4 + k4;
            const float ci = cb[kt * 16 + row16];
            const short* pb = eb + kt * 1024;
            short8 bh0 = *(const short8*)(pb + lane * 8);
            short8 bh1 = *(const short8*)(pb + 512 + lane * 8);
            short8 bl0 = *(const short8*)(pb + 8192 + lane * 8);
            short8 bl1 = *(const short8*)(pb + 8192 + 512 + lane * 8);
            const int kk = c * 128 + kt * 16 + row16;
#pragma unroll
            for (int rt = 0; rt < 2; ++rt) {
                f32x4 a2 = (f32x4){0.f, 0.f, 0.f, 0.f};
                a2 = __builtin_amdgcn_mfma_f32_16x16x32_bf16(a_hi[rt][0], bh0, a2, 0, 0, 0);
                a2 = __builtin_amdgcn_mfma_f32_16x16x32_bf16(a_hi[rt][1], bh1, a2, 0, 0, 0);
                a2 = __builtin_amdgcn_mfma_f32_16x16x32_bf16(a_lo[rt][0], bh0, a2, 0, 0, 0);
                a2 = __builtin_amdgcn_mfma_f32_16x16x32_bf16(a_lo[rt][1], bh1, a2, 0, 0, 0);
                a2 = __builtin_amdgcn_mfma_f32_16x16x32_bf16(a_hi[rt][0], bl0, a2, 0, 0, 0);
                a2 = __builtin_amdgcn_mfma_f32_16x16x32_bf16(a_hi[rt][1], bl1, a2, 0, 0, 0);
#pragma unroll
                for (int rg = 0; rg < 4; ++rg) {
                    float v = a2[rg] + ci;
                    if (v > vmax[rt][rg]) { vmax[rt][rg] = v; vidx[rt][rg] = kk; }
                }
            }
        }
        __syncthreads();
    }

    // 16-lane k-reduce (tie -> lowest idx), then merge kh halves via LDS.
    float s = 0.f;
#pragma unroll
    for (int rt = 0; rt < 2; ++rt)
#pragma unroll
        for (int rg = 0; rg < 4; ++rg) {
            float v = vmax[rt][rg];
            int ix = vidx[rt][rg];
#pragma unroll
            for (int m = 1; m < 16; m <<= 1) {
                float ov = __shfl_xor(v, m, 64);
                int   oi = __shfl_xor(ix, m, 64);
                if (ov > v || (ov == v && oi < ix)) { v = ov; ix = oi; }
            }
            vmax[rt][rg] = v; vidx[rt][rg] = ix;
        }
    if (kh == 1 && row16 == 0) {
#pragma unroll
        for (int rt = 0; rt < 2; ++rt)
#pragma unroll
            for (int rg = 0; rg < 4; ++rg) {
                const int row = (2 * pair + rt) * 16 + quad * 4 + rg;
                vtmp[row] = vmax[rt][rg];
                itmp[row] = vidx[rt][rg];
            }
    }
    __syncthreads();
    if (kh == 0) {
        if (row16 == 0) {
#pragma unroll
            for (int rt = 0; rt < 2; ++rt)
#pragma unroll
                for (int rg = 0; rg < 4; ++rg) {
                    const int row = (2 * pair + rt) * 16 + quad * 4 + rg;
                    float v = vmax[rt][rg];
                    int ix = vidx[rt][rg];
                    const float ov = vtmp[row];
                    const int   oi = itmp[row];
                    if (ov > v || (ov == v && oi < ix)) { v = ov; ix = oi; }
                    qsm[row] = ix;
                    atomicAdd(&hist[ix], 1);
                    s += v;
                }
        }
        s += __shfl_xor(s, 16, 64);
        s += __shfl_xor(s, 32, 64);
        if (lane == 0) atomicAdd(lossacc, -2.f * s);
    }
    __syncthreads();

    // ---------------- Fused gather + transpose ----------------
    {
        const int r = tid >> 2, piece = tid & 3;
        const float* src = embed + (size_t)qsm[r] * 64 + piece * 16;
        float* dst = tile + r * 69 + piece * 16;
#pragma unroll
        for (int j = 0; j < 4; ++j)
            *(float4*)(dst + j * 4) = *(const float4*)(src + j * 4);
    }
    __syncthreads();
    {
        const int tt = tid & 63;
        const int eo = tid >> 6;
        float* ob = out + ((size_t)b * 64) * T_ + t0;
#pragma unroll
        for (int j = 0; j < 8; ++j) {
            const int e = j * 8 + eo;
            ob[(size_t)e * T_ + tt]      = tile[tt * 69 + e];
            ob[(size_t)e * T_ + 64 + tt] = tile[(tt + 64) * 69 + e];
        }
    }
}

// ---------------------------------------------------------------------------
// Fused fallback (verified round-1 kernel) — used only if ws is too small
// for the h-image.
// ---------------------------------------------------------------------------
__global__ __launch_bounds__(512, 4) void projvq_kernel(
        const float* __restrict__ x,
        const short* __restrict__ whi, const short* __restrict__ wlo,
        const float* __restrict__ bias,
        const short* __restrict__ ehi, const short* __restrict__ elo,
        const float* __restrict__ nhcc,
        const float* __restrict__ embed, float* __restrict__ out,
        int* __restrict__ hist, float* __restrict__ lossacc) {
    __shared__ __align__(16) char smem[68096];
    float* xsf  = (float*)smem;
    short* es   = (short*)smem;
    short* aimg = (short*)(smem + 32768);
    float* ccs  = (float*)(smem + 65536);
    int*   qsm  = (int*)(smem + 66560);
    float* vtmp = (float*)(smem + 67072);
    int*   itmp = (int*)(smem + 67584);
    float* tile = (float*)smem;

    const int tid = threadIdx.x;
    const int wave = tid >> 6, lane = tid & 63;
    const int row16 = lane & 15, quad = lane >> 4;
    const int b  = blockIdx.x >> 5;
    const int t0 = (blockIdx.x & 31) * 128;
    const float* xb = x + (size_t)b * C_ * T_ + t0;

    f32x4 cc = *(const f32x4*)(nhcc + tid * 4);

    f32x4 acc[4];
#pragma unroll
    for (int et = 0; et < 4; ++et) acc[et] = (f32x4){0.f, 0.f, 0.f, 0.f};

#pragma unroll
    for (int j = 0; j < 2; ++j) {
        int o = j * 512 + tid;
        gl16(xb + (size_t)(o >> 5) * T_ + (o & 31) * 4, xsf + o * 4);
    }
    __syncthreads();

    for (int it = 0; it < 16; ++it) {
        const int c0 = it * 32;
        const int p = it & 1;
        if (it < 15) {
#pragma unroll
            for (int j = 0; j < 2; ++j) {
                int o = j * 512 + tid;
                gl16(xb + (size_t)(c0 + 32 + (o >> 5)) * T_ + (o & 31) * 4,
                     xsf + (p ^ 1) * 4096 + o * 4);
            }
        }
        const float* xsb = xsf + p * 4096;
        short8 bh, bl;
#pragma unroll
        for (int j = 0; j < 8; ++j) {
            float v = xsb[(quad * 8 + j) * 128 + wave * 16 + row16];
            HiLo r = split_rne(v);
            bh[j] = r.hi; bl[j] = r.lo;
        }
#pragma unroll
        for (int et = 0; et < 4; ++et) {
            size_t aoff = (size_t)(et * 16 + row16) * C_ + c0 + quad * 8;
            short8 ah = *(const short8*)(whi + aoff);
            short8 al = *(const short8*)(wlo + aoff);
            acc[et] = __builtin_amdgcn_mfma_f32_16x16x32_bf16(ah, bh, acc[et], 0, 0, 0);
            acc[et] = __builtin_amdgcn_mfma_f32_16x16x32_bf16(al, bh, acc[et], 0, 0, 0);
            acc[et] = __builtin_amdgcn_mfma_f32_16x16x32_bf16(ah, bl, acc[et], 0, 0, 0);
            acc[et] = __builtin_amdgcn_mfma_f32_16x16x32_bf16(al, bl, acc[et], 0, 0, 0);
        }
        __syncthreads();
    }

#pragma unroll
    for (int j = 0; j < 2; ++j) {
        int o = (j * 512 + tid) * 8;
        gl16(ehi + o, es + o);
        gl16(elo + o, es + 8192 + o);
    }

    float hh = 0.f;
#pragma unroll
    for (int et = 0; et < 4; ++et) {
        float4 bv = *(const float4*)(bias + et * 16 + quad * 4);
        f32x4 a = acc[et];
        a[0] += bv.x; a[1] += bv.y; a[2] += bv.z; a[3] += bv.w;
        hh = fmaf(a[0], a[0], hh); hh = fmaf(a[1], a[1], hh);
        hh = fmaf(a[2], a[2], hh); hh = fmaf(a[3], a[3], hh);
        short4v hv, lv;
#pragma unroll
        for (int r = 0; r < 4; ++r) {
            HiLo sp = split_rne(a[r]);
            hv[r] = sp.hi; lv[r] = sp.lo;
        }
        const int ks = et >> 1;
        const int qe = (et & 1) * 2 + (quad >> 1);
        const int j0 = (quad & 1) * 4;
        const int sl = ((wave * 2 + ks) * 64 + qe * 16 + row16) * 8 + j0;
        *(short4v*)(aimg + sl) = hv;
        *(short4v*)(aimg + 8192 + sl) = lv;
    }
#pragma unroll
    for (int m = 1; m < 64; m <<= 1) hh += __shfl_xor(hh, m, 64);
    if (lane == 0) atomicAdd(lossacc, hh);
    __syncthreads();

    const int pair = wave & 3, kh = wave >> 2;
    short8 a_hi[2][2], a_lo[2][2];
#pragma unroll
    for (int rt = 0; rt < 2; ++rt)
#pragma unroll
        for (int ks = 0; ks < 2; ++ks) {
            int sl = (((2 * pair + rt) * 2 + ks) * 64 + lane) * 8;
            a_hi[rt][ks] = *(const short8*)(aimg + sl);
            a_lo[rt][ks] = *(const short8*)(aimg + 8192 + sl);
        }
    if ((tid >> 5) == 0) *(f32x4*)(ccs + (tid & 31) * 4) = cc;
    __syncthreads();

    float vmax[2][4];
    int   vidx[2][4];
#pragma unroll
    for (int rt = 0; rt < 2; ++rt)
#pragma unroll
        for (int rg = 0; rg < 4; ++rg) { vmax[rt][rg] = -3.4e38f; vidx[rt][rg] = 0; }

    for (int c = 0; c < 16; ++c) {
        if (c < 15) {
            const short* sh  = ehi + (c + 1) * 8192;
            const short* sl2 = elo + (c + 1) * 8192;
            short* dst = es + ((c + 1) & 1) * 16384;
#pragma unroll
            for (int j = 0; j < 2; ++j) {
                int o = (j * 512 + tid) * 8;
                gl16(sh + o, dst + o);
                gl16(sl2 + o, dst + 8192 + o);
            }
            if ((tid >> 5) == c + 1)
                *(f32x4*)(ccs + ((c + 1) & 1) * 128 + (tid & 31) * 4) = cc;
        }
        const short* eb = es + (c & 1) * 16384;
        const float* cb = ccs + (c & 1) * 128;
#pragma unroll
        for (int k4 = 0; k4 < 4; ++k4) {
            const int kt = kh * 4 + k4;
            const float ci = cb[kt * 16 + row16];
            const short* pb = eb + kt * 1024;
            short8 bh0 = *(const short8*)(pb + lane * 8);
            short8 bh1 = *(const short8*)(pb + 512 + lane * 8);
            short8 bl0 = *(const short8*)(pb + 8192 + lane * 8);
            short8 bl1 = *(const short8*)(pb + 8192 + 512 + lane * 8);
            const int kk = c * 128 + kt * 16 + row16;
#pragma unroll
            for (int rt = 0; rt < 2; ++rt) {
                f32x4 a2 = (f32x4){0.f, 0.f, 0.f, 0.f};
                a2 = __builtin_amdgcn_mfma_f32_16x16x32_bf16(a_hi[rt][0], bh0, a2, 0, 0, 0);
                a2 = __builtin_amdgcn_mfma_f32_16x16x32_bf16(a_hi[rt][1], bh1, a2, 0, 0, 0);
                a2 = __builtin_amdgcn_mfma_f32_16x16x32_bf16(a_lo[rt][0], bh0, a2, 0, 0, 0);
                a2 = __builtin_amdgcn_mfma_f32_16x16x32_bf16(a_lo[rt][1], bh1, a2, 0, 0, 0);
                a2 = __builtin_amdgcn_mfma_f32_16x16x32_bf16(a_hi[rt][0], bl0, a2, 0, 0, 0);
                a2 = __builtin_amdgcn_mfma_f32_16x16x32_bf16(a_hi[rt][1], bl1, a2, 0, 0, 0);
#pragma unroll
                for (int rg = 0; rg < 4; ++rg) {
                    float v = a2[rg] + ci;
                    if (v > vmax[rt][rg]) { vmax[rt][rg] = v; vidx[rt][rg] = kk; }
                }
            }
        }
        __syncthreads();
    }

    float s = 0.f;
#pragma unroll
    for (int rt = 0; rt < 2; ++rt)
#pragma unroll
        for (int rg = 0; rg < 4; ++rg) {
            float v = vmax[rt][rg];
            int ix = vidx[rt][rg];
#pragma unroll
            for (int m = 1; m < 16; m <<= 1) {
                float ov = __shfl_xor(v, m, 64);
                int   oi = __shfl_xor(ix, m, 64);
                if (ov > v || (ov == v && oi < ix)) { v = ov; ix = oi; }
            }
            vmax[rt][rg] = v; vidx[rt][rg] = ix;
        }
    if (kh == 1 && row16 == 0) {
#pragma unroll
        for (int rt = 0; rt < 2; ++rt)
#pragma unroll
            for (int rg = 0; rg < 4; ++rg) {
                const int row = (2 * pair + rt) * 16 + quad * 4 + rg;
                vtmp[row] = vmax[rt][rg];
                itmp[row] = vidx[rt][rg];
            }
    }
    __syncthreads();
    if (kh == 0) {
        if (row16 == 0) {
#pragma unroll
            for (int rt = 0; rt < 2; ++rt)
#pragma unroll
                for (int rg = 0; rg < 4; ++rg) {
                    const int row = (2 * pair + rt) * 16 + quad * 4 + rg;
                    float v = vmax[rt][rg];
                    int ix = vidx[rt][rg];
                    const float ov = vtmp[row];
                    const int   oi = itmp[row];
                    if (ov > v || (ov == v && oi < ix)) { v = ov; ix = oi; }
                    qsm[row] = ix;
                    atomicAdd(&hist[ix], 1);
                    s += v;
                }
        }
        s += __shfl_xor(s, 16, 64);
        s += __shfl_xor(s, 32, 64);
        if (lane == 0) atomicAdd(lossacc, -2.f * s);
    }
    __syncthreads();

    {
        const int r = tid >> 2, piece = tid & 3;
        const float* src = embed + (size_t)qsm[r] * 64 + piece * 16;
        float* dst = tile + r * 69 + piece * 16;
#pragma unroll
        for (int j = 0; j < 4; ++j)
            *(float4*)(dst + j * 4) = *(const float4*)(src + j * 4);
    }
    __syncthreads();
    {
        const int tt = tid & 63;
        const int eo = tid >> 6;
        float* ob = out + ((size_t)b * 64) * T_ + t0;
#pragma unroll
        for (int j = 0; j < 8; ++j) {
            const int e = j * 8 + eo;
            ob[(size_t)e * T_ + tt]      = tile[tt * 69 + e];
            ob[(size_t)e * T_ + 64 + tt] = tile[(tt + 64) * 69 + e];
        }
    }
}

// ---------------------------------------------------------------------------
// Finalize: loss, kldiv constant, log-perplexity.
// ---------------------------------------------------------------------------
__global__ void finalize_kernel(const int* __restrict__ hist,
                                const float* __restrict__ lossacc,
                                float* __restrict__ out) {
    __shared__ float red[4];
    const int tid = threadIdx.x;
    float s = 0.f;
    for (int k = tid; k < K_; k += 256) {
        float p = (float)hist[k] * (1.f / 65536.f);
        s -= p * logf(p + 1e-10f);
    }
#pragma unroll
    for (int m = 1; m < 64; m <<= 1) s += __shfl_xor(s, m, 64);
    if ((tid & 63) == 0) red[tid >> 6] = s;
    __syncthreads();
    if (tid == 0) {
        float lp = red[0] + red[1] + red[2] + red[3];
        out[ZQ_ELEMS] = 0.25f * lossacc[0] / (float)ZQ_ELEMS;    // loss
        out[ZQ_ELEMS + 17] = lp;                                  // log_perplexity
    }
    if (tid < 16) out[ZQ_ELEMS + 1 + tid] = logf(2048.f) * 4096.f;  // kldiv_r
}

// ---------------------------------------------------------------------------
extern "C" void kernel_launch(void* const* d_in, const int* in_sizes, int n_in,
                              void* d_out, int out_size, void* d_ws, size_t ws_size,
                              hipStream_t stream) {
    const float* x      = (const float*)d_in[0];
    const float* proj_w = (const float*)d_in[1];
    const float* proj_b = (const float*)d_in[2];
    const float* embed  = (const float*)d_in[3];
    float* out = (float*)d_out;
    char* ws = (char*)d_ws;

    short* e_hi = (short*)(ws + WS_EHI);
    short* e_lo = (short*)(ws + WS_ELO);
    float* nhcc = (float*)(ws + WS_NHCC);
    short* w_hi = (short*)(ws + WS_WHI);
    short* w_lo = (short*)(ws + WS_WLO);
    int*   hist = (int*)(ws + WS_HIST);
    float* lossac = (float*)(ws + WS_LOSS);
    short* himg = (short*)(ws + WS_HIMG);

    // hist + loss adjacent; zero both (ws poisoned 0xAA each launch).
    (void)hipMemsetAsync(ws + WS_HIST, 0, K_ * sizeof(int) + sizeof(float), stream);

    prep_kernel<<<96, 256, 0, stream>>>(embed, proj_w, e_hi, e_lo, nhcc, w_hi, w_lo);
    if (ws_size >= (size_t)WS_NEED) {
        proj_kernel<<<1024, 256, 0, stream>>>(x, w_hi, w_lo, proj_b, himg, lossac);
        vq_kernel<<<512, 512, 0, stream>>>(himg, e_hi, e_lo, nhcc, embed, out,
                                           hist, lossac);
    } else {
        projvq_kernel<<<N_ / 128, 512, 0, stream>>>(x, w_hi, w_lo, proj_b,
                                                    e_hi, e_lo, nhcc, embed, out,
                                                    hist, lossac);
    }
    finalize_kernel<<<1, 256, 0, stream>>>(hist, lossac, out);
}

// Round 3
// 343.401 us; speedup vs baseline: 1.0029x; 1.0029x over previous
//
#include <hip/hip_runtime.h>
#include <math.h>

// Problem constants (from reference)
#define B_ 16
#define T_ 4096
#define C_ 512
#define E_ 64
#define K_ 2048
#define N_ (B_*T_)          // 65536
#define ZQ_ELEMS 4194304    // B*E*T

typedef __attribute__((ext_vector_type(8))) short short8;
typedef __attribute__((ext_vector_type(4))) short short4v;
typedef __attribute__((ext_vector_type(4))) float f32x4;

// ws layout (bytes):
//   ehi_sw : [16][8192] bf16 B-frag-tiled codebook hi @ 0       (256 KB)
//   elo_sw : lo plane                              @ 262144     (256 KB)
//   nhcc   : [K] f32 (-0.5*||e_k||^2)              @ 524288     (8 KB)
//   w_hi   : [64][512] bf16                        @ 532480     (64 KB)
//   w_lo   : [64][512] bf16                        @ 598016     (64 KB)
//   hist   : [K] i32                               @ 663552     (8 KB)  <- memset w/ loss
//   loss   : f32                                   @ 671744     (4 B)
//   himg   : [512 groups][16384] shorts (hi 8192 | lo 8192) @ 1 MB (16.78 MB)
#define WS_EHI   0
#define WS_ELO   262144
#define WS_NHCC  524288
#define WS_WHI   532480
#define WS_WLO   598016
#define WS_HIST  663552
#define WS_LOSS  671744
#define WS_HIMG  1048576
#define WS_NEED  (WS_HIMG + 512*16384*2)   // ~17.8 MB

struct HiLo { short hi, lo; };

__device__ __forceinline__ unsigned short rne16(float v) {
    unsigned u = __float_as_uint(v);
    return (unsigned short)((u + 0x7FFFu + ((u >> 16) & 1u)) >> 16);
}
__device__ __forceinline__ HiLo split_rne(float v) {
    HiLo r;
    unsigned hb = rne16(v);
    r.hi = (short)hb;
    float hf = __uint_as_float((unsigned)hb << 16);
    r.lo = (short)rne16(v - hf);
    return r;
}

// Async global->LDS, 16B per lane (used by the fused fallback only).
typedef const __attribute__((address_space(1))) void* gas1_t;
typedef __attribute__((address_space(3))) void* las3_t;
__device__ __forceinline__ void gl16(const void* g, void* l) {
    __builtin_amdgcn_global_load_lds((gas1_t)g, (las3_t)l, 16, 0, 0);
}

// ---------------------------------------------------------------------------
// Prep. Blocks 0..63: embed -> B-frag-tiled bf16 hi/lo + nhcc.
//       Blocks 64..95: W -> flat bf16 hi/lo.
// Tiled layout per 128-k chunk (8192 shorts/plane): slot for (r=k&127, e):
//   kt=r>>4, col=r&15, ks=e>>5, qe=(e>>3)&3 -> ((kt*2+ks)*64 + qe*16 + col)*8 + (e&7)
// so a vq wave's B-frag read (pb + lane*8) is a coalesced 1 KB run — works
// directly from global (L2-resident), no LDS staging required.
// ---------------------------------------------------------------------------
__global__ void prep_kernel(const float* __restrict__ embed,
                            const float* __restrict__ W,
                            short* __restrict__ ehi, short* __restrict__ elo,
                            float* __restrict__ nhcc,
                            short* __restrict__ whi, short* __restrict__ wlo) {
    const int tid = threadIdx.x;
    if (blockIdx.x < 64) {
        const int row = blockIdx.x * 32 + (tid >> 3);
        const int g = tid & 7;
        const float* src = embed + (size_t)row * 64 + g * 8;
        short8 hv, lv;
        float s = 0.f;
#pragma unroll
        for (int j = 0; j < 8; ++j) {
            float v = src[j];
            s = fmaf(v, v, s);
            HiLo r = split_rne(v);
            hv[j] = r.hi; lv[j] = r.lo;
        }
        const int c128 = row >> 7, r = row & 127;
        const int kt = r >> 4, col = r & 15, ks = g >> 2, qe = g & 3;
        const int slot = (kt * 2 + ks) * 64 + qe * 16 + col;
        *(short8*)(ehi + c128 * 8192 + slot * 8) = hv;
        *(short8*)(elo + c128 * 8192 + slot * 8) = lv;
        s += __shfl_xor(s, 1, 64);
        s += __shfl_xor(s, 2, 64);
        s += __shfl_xor(s, 4, 64);
        if (g == 0) nhcc[row] = -0.5f * s;
    } else {
        int idx = ((blockIdx.x - 64) * 256 + tid) * 4;
        float4 v = *(const float4*)(W + idx);
        short4v h, l;
        HiLo a = split_rne(v.x); h[0] = a.hi; l[0] = a.lo;
        HiLo b = split_rne(v.y); h[1] = b.hi; l[1] = b.lo;
        HiLo c = split_rne(v.z); h[2] = c.hi; l[2] = c.lo;
        HiLo d = split_rne(v.w); h[3] = d.hi; l[3] = d.lo;
        *(short4v*)(whi + idx) = h;
        *(short4v*)(wlo + idx) = l;
    }
}

// ---------------------------------------------------------------------------
// proj_kernel (barrier-free): h = W.x + bias for a 64-t tile; writes bf16
// hi/lo h-image in A-frag order to himg.
// NO LDS, NO barriers: each lane loads its 8 B-frag c-values directly from
// global (x fits in L3; 64 B coalesced segments per 16-lane group), with a
// 2-stage software pipeline (chunk i+1 loads issued during chunk i compute).
// Full unroll -> compiler schedules loads deep ahead; latency hidden by
// ILP + 16 waves/CU instead of barrier-drained prefetch.
// Block 256 thr (4 waves, one 16-t tile each). Grid 1024 (= B * T/64).
// ---------------------------------------------------------------------------
__global__ __launch_bounds__(256, 4) void proj_kernel(
        const float* __restrict__ x,
        const short* __restrict__ whi, const short* __restrict__ wlo,
        const float* __restrict__ bias,
        short* __restrict__ himg, float* __restrict__ lossacc) {
    const int tid = threadIdx.x;
    const int wave = tid >> 6, lane = tid & 63;
    const int row16 = lane & 15, quad = lane >> 4;
    const int blk = blockIdx.x;
    const int b  = blk >> 6;
    const int t0 = (blk & 63) * 64;
    // this lane's t-column
    const float* xl = x + (size_t)b * C_ * T_ + t0 + wave * 16 + row16;

    f32x4 acc[4];
#pragma unroll
    for (int et = 0; et < 4; ++et) acc[et] = (f32x4){0.f, 0.f, 0.f, 0.f};

    float xv[8];
#pragma unroll
    for (int j = 0; j < 8; ++j)
        xv[j] = xl[(size_t)(quad * 8 + j) * T_];

#pragma unroll
    for (int it = 0; it < 16; ++it) {
        const int c0 = it * 32;
        float xn[8];
        if (it < 15) {
#pragma unroll
            for (int j = 0; j < 8; ++j)
                xn[j] = xl[(size_t)(c0 + 32 + quad * 8 + j) * T_];
        }
        short8 bh, bl;
#pragma unroll
        for (int j = 0; j < 8; ++j) {
            HiLo r = split_rne(xv[j]);
            bh[j] = r.hi; bl[j] = r.lo;
        }
#pragma unroll
        for (int et = 0; et < 4; ++et) {
            size_t aoff = (size_t)(et * 16 + row16) * C_ + c0 + quad * 8;
            short8 ah = *(const short8*)(whi + aoff);
            short8 al = *(const short8*)(wlo + aoff);
            acc[et] = __builtin_amdgcn_mfma_f32_16x16x32_bf16(ah, bh, acc[et], 0, 0, 0);
            acc[et] = __builtin_amdgcn_mfma_f32_16x16x32_bf16(al, bh, acc[et], 0, 0, 0);
            acc[et] = __builtin_amdgcn_mfma_f32_16x16x32_bf16(ah, bl, acc[et], 0, 0, 0);
            acc[et] = __builtin_amdgcn_mfma_f32_16x16x32_bf16(al, bl, acc[et], 0, 0, 0);
        }
        if (it < 15) {
#pragma unroll
            for (int j = 0; j < 8; ++j) xv[j] = xn[j];
        }
    }

    // Epilogue: bias, ||h||^2, store h hi/lo in A-frag order to himg.
    // 128-row group g = blk>>1; this block's waves are w2 = (blk&1)*4 + wave.
    short* gb = himg + (size_t)(blk >> 1) * 16384;
    const int w2 = (blk & 1) * 4 + wave;
    float hh = 0.f;
#pragma unroll
    for (int et = 0; et < 4; ++et) {
        float4 bv = *(const float4*)(bias + et * 16 + quad * 4);
        f32x4 a = acc[et];
        a[0] += bv.x; a[1] += bv.y; a[2] += bv.z; a[3] += bv.w;
        hh = fmaf(a[0], a[0], hh); hh = fmaf(a[1], a[1], hh);
        hh = fmaf(a[2], a[2], hh); hh = fmaf(a[3], a[3], hh);
        short4v hv, lv;
#pragma unroll
        for (int r = 0; r < 4; ++r) {
            HiLo sp = split_rne(a[r]);
            hv[r] = sp.hi; lv[r] = sp.lo;
        }
        const int ks = et >> 1;
        const int qe = (et & 1) * 2 + (quad >> 1);
        const int j0 = (quad & 1) * 4;
        const int sl = ((w2 * 2 + ks) * 64 + qe * 16 + row16) * 8 + j0;
        *(short4v*)(gb + sl) = hv;
        *(short4v*)(gb + 8192 + sl) = lv;
    }
#pragma unroll
    for (int m = 1; m < 64; m <<= 1) hh += __shfl_xor(hh, m, 64);
    if (lane == 0) atomicAdd(lossacc, hh);
}

// ---------------------------------------------------------------------------
// vq_kernel (barrier-free scan): argmin over K=2048 codes + fused gather.
// Codebook fragments load DIRECTLY from global (tiled layout -> pb + lane*8
// is a coalesced 1 KB wave read; codebook 512 KB = L2-resident). nhcc read
// directly per k-tile. No es/ccs staging, no barriers in the 16-chunk scan.
// LDS only for argmax merge + gather tile (36 KB).
// Block 512 thr (8 waves) = one 128-row group; kh-split. Grid 512.
// ---------------------------------------------------------------------------
__global__ __launch_bounds__(512, 4) void vq_kernel(
        const short* __restrict__ himg,
        const short* __restrict__ ehi, const short* __restrict__ elo,
        const float* __restrict__ nhcc,
        const float* __restrict__ embed, float* __restrict__ out,
        int* __restrict__ hist, float* __restrict__ lossacc) {
    __shared__ __align__(16) float tile[128 * 69];   // 35328 B (gather)
    __shared__ int   qsm[128];
    __shared__ float vtmp[128];
    __shared__ int   itmp[128];

    const int tid = threadIdx.x;
    const int wave = tid >> 6, lane = tid & 63;
    const int row16 = lane & 15, quad = lane >> 4;
    const int g = blockIdx.x;
    const int b  = g >> 5;
    const int t0 = (g & 31) * 128;

    // A-frags: lane-linear from global h-image.
    const short* gb = himg + (size_t)g * 16384;
    const int pair = wave & 3, kh = wave >> 2;
    short8 a_hi[2][2], a_lo[2][2];
#pragma unroll
    for (int rt = 0; rt < 2; ++rt)
#pragma unroll
        for (int ks = 0; ks < 2; ++ks) {
            int sl = (((2 * pair + rt) * 2 + ks) * 64 + lane) * 8;
            a_hi[rt][ks] = *(const short8*)(gb + sl);
            a_lo[rt][ks] = *(const short8*)(gb + 8192 + sl);
        }

    float vmax[2][4];
    int   vidx[2][4];
#pragma unroll
    for (int rt = 0; rt < 2; ++rt)
#pragma unroll
        for (int rg = 0; rg < 4; ++rg) { vmax[rt][rg] = -3.4e38f; vidx[rt][rg] = 0; }

    for (int c = 0; c < 16; ++c) {
        const short* hb = ehi + c * 8192;
        const short* lb = elo + c * 8192;
#pragma unroll
        for (int k4 = 0; k4 < 4; ++k4) {
            const int kt = kh * 4 + k4;
            const short* pb = hb + kt * 1024;
            const short* pl = lb + kt * 1024;
            short8 bh0 = *(const short8*)(pb + lane * 8);
            short8 bh1 = *(const short8*)(pb + 512 + lane * 8);
            short8 bl0 = *(const short8*)(pl + lane * 8);
            short8 bl1 = *(const short8*)(pl + 512 + lane * 8);
            const int kk = c * 128 + kt * 16 + row16;
            const float ci = nhcc[kk];
#pragma unroll
            for (int rt = 0; rt < 2; ++rt) {
                f32x4 a2 = (f32x4){0.f, 0.f, 0.f, 0.f};
                a2 = __builtin_amdgcn_mfma_f32_16x16x32_bf16(a_hi[rt][0], bh0, a2, 0, 0, 0);
                a2 = __builtin_amdgcn_mfma_f32_16x16x32_bf16(a_hi[rt][1], bh1, a2, 0, 0, 0);
                a2 = __builtin_amdgcn_mfma_f32_16x16x32_bf16(a_lo[rt][0], bh0, a2, 0, 0, 0);
                a2 = __builtin_amdgcn_mfma_f32_16x16x32_bf16(a_lo[rt][1], bh1, a2, 0, 0, 0);
                a2 = __builtin_amdgcn_mfma_f32_16x16x32_bf16(a_hi[rt][0], bl0, a2, 0, 0, 0);
                a2 = __builtin_amdgcn_mfma_f32_16x16x32_bf16(a_hi[rt][1], bl1, a2, 0, 0, 0);
#pragma unroll
                for (int rg = 0; rg < 4; ++rg) {
                    float v = a2[rg] + ci;
                    if (v > vmax[rt][rg]) { vmax[rt][rg] = v; vidx[rt][rg] = kk; }
                }
            }
        }
    }

    // 16-lane k-reduce (tie -> lowest idx), then merge kh halves via LDS.
    float s = 0.f;
#pragma unroll
    for (int rt = 0; rt < 2; ++rt)
#pragma unroll
        for (int rg = 0; rg < 4; ++rg) {
            float v = vmax[rt][rg];
            int ix = vidx[rt][rg];
#pragma unroll
            for (int m = 1; m < 16; m <<= 1) {
                float ov = __shfl_xor(v, m, 64);
                int   oi = __shfl_xor(ix, m, 64);
                if (ov > v || (ov == v && oi < ix)) { v = ov; ix = oi; }
            }
            vmax[rt][rg] = v; vidx[rt][rg] = ix;
        }
    if (kh == 1 && row16 == 0) {
#pragma unroll
        for (int rt = 0; rt < 2; ++rt)
#pragma unroll
            for (int rg = 0; rg < 4; ++rg) {
                const int row = (2 * pair + rt) * 16 + quad * 4 + rg;
                vtmp[row] = vmax[rt][rg];
                itmp[row] = vidx[rt][rg];
            }
    }
    __syncthreads();
    if (kh == 0) {
        if (row16 == 0) {
#pragma unroll
            for (int rt = 0; rt < 2; ++rt)
#pragma unroll
                for (int rg = 0; rg < 4; ++rg) {
                    const int row = (2 * pair + rt) * 16 + quad * 4 + rg;
                    float v = vmax[rt][rg];
                    int ix = vidx[rt][rg];
                    const float ov = vtmp[row];
                    const int   oi = itmp[row];
                    if (ov > v || (ov == v && oi < ix)) { v = ov; ix = oi; }
                    qsm[row] = ix;
                    atomicAdd(&hist[ix], 1);
                    s += v;
                }
        }
        s += __shfl_xor(s, 16, 64);
        s += __shfl_xor(s, 32, 64);
        if (lane == 0) atomicAdd(lossacc, -2.f * s);
    }
    __syncthreads();

    // ---------------- Fused gather + transpose ----------------
    {
        const int r = tid >> 2, piece = tid & 3;
        const float* src = embed + (size_t)qsm[r] * 64 + piece * 16;
        float* dst = tile + r * 69 + piece * 16;
#pragma unroll
        for (int j = 0; j < 4; ++j)
            *(float4*)(dst + j * 4) = *(const float4*)(src + j * 4);
    }
    __syncthreads();
    {
        const int tt = tid & 63;
        const int eo = tid >> 6;
        float* ob = out + ((size_t)b * 64) * T_ + t0;
#pragma unroll
        for (int j = 0; j < 8; ++j) {
            const int e = j * 8 + eo;
            ob[(size_t)e * T_ + tt]      = tile[tt * 69 + e];
            ob[(size_t)e * T_ + 64 + tt] = tile[(tt + 64) * 69 + e];
        }
    }
}

// ---------------------------------------------------------------------------
// Fused fallback (verified round-1 kernel) — used only if ws is too small
// for the h-image.
// ---------------------------------------------------------------------------
__global__ __launch_bounds__(512, 4) void projvq_kernel(
        const float* __restrict__ x,
        const short* __restrict__ whi, const short* __restrict__ wlo,
        const float* __restrict__ bias,
        const short* __restrict__ ehi, const short* __restrict__ elo,
        const float* __restrict__ nhcc,
        const float* __restrict__ embed, float* __restrict__ out,
        int* __restrict__ hist, float* __restrict__ lossacc) {
    __shared__ __align__(16) char smem[68096];
    float* xsf  = (float*)smem;
    short* es   = (short*)smem;
    short* aimg = (short*)(smem + 32768);
    float* ccs  = (float*)(smem + 65536);
    int*   qsm2 = (int*)(smem + 66560);
    float* vtmp = (float*)(smem + 67072);
    int*   itmp = (int*)(smem + 67584);
    float* tile = (float*)smem;

    const int tid = threadIdx.x;
    const int wave = tid >> 6, lane = tid & 63;
    const int row16 = lane & 15, quad = lane >> 4;
    const int b  = blockIdx.x >> 5;
    const int t0 = (blockIdx.x & 31) * 128;
    const float* xb = x + (size_t)b * C_ * T_ + t0;

    f32x4 cc = *(const f32x4*)(nhcc + tid * 4);

    f32x4 acc[4];
#pragma unroll
    for (int et = 0; et < 4; ++et) acc[et] = (f32x4){0.f, 0.f, 0.f, 0.f};

#pragma unroll
    for (int j = 0; j < 2; ++j) {
        int o = j * 512 + tid;
        gl16(xb + (size_t)(o >> 5) * T_ + (o & 31) * 4, xsf + o * 4);
    }
    __syncthreads();

    for (int it = 0; it < 16; ++it) {
        const int c0 = it * 32;
        const int p = it & 1;
        if (it < 15) {
#pragma unroll
            for (int j = 0; j < 2; ++j) {
                int o = j * 512 + tid;
                gl16(xb + (size_t)(c0 + 32 + (o >> 5)) * T_ + (o & 31) * 4,
                     xsf + (p ^ 1) * 4096 + o * 4);
            }
        }
        const float* xsb = xsf + p * 4096;
        short8 bh, bl;
#pragma unroll
        for (int j = 0; j < 8; ++j) {
            float v = xsb[(quad * 8 + j) * 128 + wave * 16 + row16];
            HiLo r = split_rne(v);
            bh[j] = r.hi; bl[j] = r.lo;
        }
#pragma unroll
        for (int et = 0; et < 4; ++et) {
            size_t aoff = (size_t)(et * 16 + row16) * C_ + c0 + quad * 8;
            short8 ah = *(const short8*)(whi + aoff);
            short8 al = *(const short8*)(wlo + aoff);
            acc[et] = __builtin_amdgcn_mfma_f32_16x16x32_bf16(ah, bh, acc[et], 0, 0, 0);
            acc[et] = __builtin_amdgcn_mfma_f32_16x16x32_bf16(al, bh, acc[et], 0, 0, 0);
            acc[et] = __builtin_amdgcn_mfma_f32_16x16x32_bf16(ah, bl, acc[et], 0, 0, 0);
            acc[et] = __builtin_amdgcn_mfma_f32_16x16x32_bf16(al, bl, acc[et], 0, 0, 0);
        }
        __syncthreads();
    }

#pragma unroll
    for (int j = 0; j < 2; ++j) {
        int o = (j * 512 + tid) * 8;
        gl16(ehi + o, es + o);
        gl16(elo + o, es + 8192 + o);
    }

    float hh = 0.f;
#pragma unroll
    for (int et = 0; et < 4; ++et) {
        float4 bv = *(const float4*)(bias + et * 16 + quad * 4);
        f32x4 a = acc[et];
        a[0] += bv.x; a[1] += bv.y; a[2] += bv.z; a[3] += bv.w;
        hh = fmaf(a[0], a[0], hh); hh = fmaf(a[1], a[1], hh);
        hh = fmaf(a[2], a[2], hh); hh = fmaf(a[3], a[3], hh);
        short4v hv, lv;
#pragma unroll
        for (int r = 0; r < 4; ++r) {
            HiLo sp = split_rne(a[r]);
            hv[r] = sp.hi; lv[r] = sp.lo;
        }
        const int ks = et >> 1;
        const int qe = (et & 1) * 2 + (quad >> 1);
        const int j0 = (quad & 1) * 4;
        const int sl = ((wave * 2 + ks) * 64 + qe * 16 + row16) * 8 + j0;
        *(short4v*)(aimg + sl) = hv;
        *(short4v*)(aimg + 8192 + sl) = lv;
    }
#pragma unroll
    for (int m = 1; m < 64; m <<= 1) hh += __shfl_xor(hh, m, 64);
    if (lane == 0) atomicAdd(lossacc, hh);
    __syncthreads();

    const int pair = wave & 3, kh = wave >> 2;
    short8 a_hi[2][2], a_lo[2][2];
#pragma unroll
    for (int rt = 0; rt < 2; ++rt)
#pragma unroll
        for (int ks = 0; ks < 2; ++ks) {
            int sl = (((2 * pair + rt) * 2 + ks) * 64 + lane) * 8;
            a_hi[rt][ks] = *(const short8*)(aimg + sl);
            a_lo[rt][ks] = *(const short8*)(aimg + 8192 + sl);
        }
    if ((tid >> 5) == 0) *(f32x4*)(ccs + (tid & 31) * 4) = cc;
    __syncthreads();

    float vmax[2][4];
    int   vidx[2][4];
#pragma unroll
    for (int rt = 0; rt < 2; ++rt)
#pragma unroll
        for (int rg = 0; rg < 4; ++rg) { vmax[rt][rg] = -3.4e38f; vidx[rt][rg] = 0; }

    for (int c = 0; c < 16; ++c) {
        if (c < 15) {
            const short* sh  = ehi + (c + 1) * 8192;
            const short* sl2 = elo + (c + 1) * 8192;
            short* dst = es + ((c + 1) & 1) * 16384;
#pragma unroll
            for (int j = 0; j < 2; ++j) {
                int o = (j * 512 + tid) * 8;
                gl16(sh + o, dst + o);
                gl16(sl2 + o, dst + 8192 + o);
            }
            if ((tid >> 5) == c + 1)
                *(f32x4*)(ccs + ((c + 1) & 1) * 128 + (tid & 31) * 4) = cc;
        }
        const short* eb = es + (c & 1) * 16384;
        const float* cb = ccs + (c & 1) * 128;
#pragma unroll
        for (int k4 = 0; k4 < 4; ++k4) {
            const int kt = kh * 4 + k4;
            const float ci = cb[kt * 16 + row16];
            const short* pb = eb + kt * 1024;
            short8 bh0 = *(const short8*)(pb + lane * 8);
            short8 bh1 = *(const short8*)(pb + 512 + lane * 8);
            short8 bl0 = *(const short8*)(pb + 8192 + lane * 8);
            short8 bl1 = *(const short8*)(pb + 8192 + 512 + lane * 8);
            const int kk = c * 128 + kt * 16 + row16;
#pragma unroll
            for (int rt = 0; rt < 2; ++rt) {
                f32x4 a2 = (f32x4){0.f, 0.f, 0.f, 0.f};
                a2 = __builtin_amdgcn_mfma_f32_16x16x32_bf16(a_hi[rt][0], bh0, a2, 0, 0, 0);
                a2 = __builtin_amdgcn_mfma_f32_16x16x32_bf16(a_hi[rt][1], bh1, a2, 0, 0, 0);
                a2 = __builtin_amdgcn_mfma_f32_16x16x32_bf16(a_lo[rt][0], bh0, a2, 0, 0, 0);
                a2 = __builtin_amdgcn_mfma_f32_16x16x32_bf16(a_lo[rt][1], bh1, a2, 0, 0, 0);
                a2 = __builtin_amdgcn_mfma_f32_16x16x32_bf16(a_hi[rt][0], bl0, a2, 0, 0, 0);
                a2 = __builtin_amdgcn_mfma_f32_16x16x32_bf16(a_hi[rt][1], bl1, a2, 0, 0, 0);
#pragma unroll
                for (int rg = 0; rg < 4; ++rg) {
                    float v = a2[rg] + ci;
                    if (v > vmax[rt][rg]) { vmax[rt][rg] = v; vidx[rt][rg] = kk; }
                }
            }
        }
        __syncthreads();
    }

    float s = 0.f;
#pragma unroll
    for (int rt = 0; rt < 2; ++rt)
#pragma unroll
        for (int rg = 0; rg < 4; ++rg) {
            float v = vmax[rt][rg];
            int ix = vidx[rt][rg];
#pragma unroll
            for (int m = 1; m < 16; m <<= 1) {
                float ov = __shfl_xor(v, m, 64);
                int   oi = __shfl_xor(ix, m, 64);
                if (ov > v || (ov == v && oi < ix)) { v = ov; ix = oi; }
            }
            vmax[rt][rg] = v; vidx[rt][rg] = ix;
        }
    if (kh == 1 && row16 == 0) {
#pragma unroll
        for (int rt = 0; rt < 2; ++rt)
#pragma unroll
            for (int rg = 0; rg < 4; ++rg) {
                const int row = (2 * pair + rt) * 16 + quad * 4 + rg;
                vtmp[row] = vmax[rt][rg];
                itmp[row] = vidx[rt][rg];
            }
    }
    __syncthreads();
    if (kh == 0) {
        if (row16 == 0) {
#pragma unroll
            for (int rt = 0; rt < 2; ++rt)
#pragma unroll
                for (int rg = 0; rg < 4; ++rg) {
                    const int row = (2 * pair + rt) * 16 + quad * 4 + rg;
                    float v = vmax[rt][rg];
                    int ix = vidx[rt][rg];
                    const float ov = vtmp[row];
                    const int   oi = itmp[row];
                    if (ov > v || (ov == v && oi < ix)) { v = ov; ix = oi; }
                    qsm2[row] = ix;
                    atomicAdd(&hist[ix], 1);
                    s += v;
                }
        }
        s += __shfl_xor(s, 16, 64);
        s += __shfl_xor(s, 32, 64);
        if (lane == 0) atomicAdd(lossacc, -2.f * s);
    }
    __syncthreads();

    {
        const int r = tid >> 2, piece = tid & 3;
        const float* src = embed + (size_t)qsm2[r] * 64 + piece * 16;
        float* dst = tile + r * 69 + piece * 16;
#pragma unroll
        for (int j = 0; j < 4; ++j)
            *(float4*)(dst + j * 4) = *(const float4*)(src + j * 4);
    }
    __syncthreads();
    {
        const int tt = tid & 63;
        const int eo = tid >> 6;
        float* ob = out + ((size_t)b * 64) * T_ + t0;
#pragma unroll
        for (int j = 0; j < 8; ++j) {
            const int e = j * 8 + eo;
            ob[(size_t)e * T_ + tt]      = tile[tt * 69 + e];
            ob[(size_t)e * T_ + 64 + tt] = tile[(tt + 64) * 69 + e];
        }
    }
}

// ---------------------------------------------------------------------------
// Finalize: loss, kldiv constant, log-perplexity.
// ---------------------------------------------------------------------------
__global__ void finalize_kernel(const int* __restrict__ hist,
                                const float* __restrict__ lossacc,
                                float* __restrict__ out) {
    __shared__ float red[4];
    const int tid = threadIdx.x;
    float s = 0.f;
    for (int k = tid; k < K_; k += 256) {
        float p = (float)hist[k] * (1.f / 65536.f);
        s -= p * logf(p + 1e-10f);
    }
#pragma unroll
    for (int m = 1; m < 64; m <<= 1) s += __shfl_xor(s, m, 64);
    if ((tid & 63) == 0) red[tid >> 6] = s;
    __syncthreads();
    if (tid == 0) {
        float lp = red[0] + red[1] + red[2] + red[3];
        out[ZQ_ELEMS] = 0.25f * lossacc[0] / (float)ZQ_ELEMS;    // loss
        out[ZQ_ELEMS + 17] = lp;                                  // log_perplexity
    }
    if (tid < 16) out[ZQ_ELEMS + 1 + tid] = logf(2048.f) * 4096.f;  // kldiv_r
}

// ---------------------------------------------------------------------------
extern "C" void kernel_launch(void* const* d_in, const int* in_sizes, int n_in,
                              void* d_out, int out_size, void* d_ws, size_t ws_size,
                              hipStream_t stream) {
    const float* x      = (const float*)d_in[0];
    const float* proj_w = (const float*)d_in[1];
    const float* proj_b = (const float*)d_in[2];
    const float* embed  = (const float*)d_in[3];
    float* out = (float*)d_out;
    char* ws = (char*)d_ws;

    short* e_hi = (short*)(ws + WS_EHI);
    short* e_lo = (short*)(ws + WS_ELO);
    float* nhcc = (float*)(ws + WS_NHCC);
    short* w_hi = (short*)(ws + WS_WHI);
    short* w_lo = (short*)(ws + WS_WLO);
    int*   hist = (int*)(ws + WS_HIST);
    float* lossac = (float*)(ws + WS_LOSS);
    short* himg = (short*)(ws + WS_HIMG);

    // hist + loss adjacent; zero both (ws poisoned 0xAA each launch).
    (void)hipMemsetAsync(ws + WS_HIST, 0, K_ * sizeof(int) + sizeof(float), stream);

    prep_kernel<<<96, 256, 0, stream>>>(embed, proj_w, e_hi, e_lo, nhcc, w_hi, w_lo);
    if (ws_size >= (size_t)WS_NEED) {
        proj_kernel<<<1024, 256, 0, stream>>>(x, w_hi, w_lo, proj_b, himg, lossac);
        vq_kernel<<<512, 512, 0, stream>>>(himg, e_hi, e_lo, nhcc, embed, out,
                                           hist, lossac);
    } else {
        projvq_kernel<<<N_ / 128, 512, 0, stream>>>(x, w_hi, w_lo, proj_b,
                                                    e_hi, e_lo, nhcc, embed, out,
                                                    hist, lossac);
    }
    finalize_kernel<<<1, 256, 0, stream>>>(hist, lossac, out);
}

// Round 4
// 299.926 us; speedup vs baseline: 1.1483x; 1.1450x over previous
//
#include <hip/hip_runtime.h>
#include <math.h>

// Problem constants (from reference)
#define B_ 16
#define T_ 4096
#define C_ 512
#define E_ 64
#define K_ 2048
#define N_ (B_*T_)          // 65536
#define ZQ_ELEMS 4194304    // B*E*T

typedef __attribute__((ext_vector_type(8))) short short8;
typedef __attribute__((ext_vector_type(4))) short short4v;
typedef __attribute__((ext_vector_type(4))) float f32x4;

// ws layout (bytes):
//   ehi_sw : [16][8192] bf16 B-frag-tiled codebook hi @ 0       (256 KB)
//   elo_sw : lo plane                              @ 262144     (256 KB)
//   nhcc   : [K] f32 (-0.5*||e_k||^2)              @ 524288     (8 KB)
//   w_hi   : [64][512] bf16                        @ 532480     (64 KB)
//   w_lo   : [64][512] bf16                        @ 598016     (64 KB)
//   hist   : [K] i32                               @ 663552     (8 KB)  <- memset w/ loss
//   loss   : f32                                   @ 671744     (4 B)
//   himg   : [512 groups][16384] shorts (hi 8192 | lo 8192) @ 1 MB (16.78 MB)
#define WS_EHI   0
#define WS_ELO   262144
#define WS_NHCC  524288
#define WS_WHI   532480
#define WS_WLO   598016
#define WS_HIST  663552
#define WS_LOSS  671744
#define WS_HIMG  1048576
#define WS_NEED  (WS_HIMG + 512*16384*2)   // ~17.8 MB

struct HiLo { short hi, lo; };

__device__ __forceinline__ unsigned short rne16(float v) {
    unsigned u = __float_as_uint(v);
    return (unsigned short)((u + 0x7FFFu + ((u >> 16) & 1u)) >> 16);
}
__device__ __forceinline__ HiLo split_rne(float v) {
    HiLo r;
    unsigned hb = rne16(v);
    r.hi = (short)hb;
    float hf = __uint_as_float((unsigned)hb << 16);
    r.lo = (short)rne16(v - hf);
    return r;
}

// Async global->LDS, 16B per lane (used by the fused fallback only).
typedef const __attribute__((address_space(1))) void* gas1_t;
typedef __attribute__((address_space(3))) void* las3_t;
__device__ __forceinline__ void gl16(const void* g, void* l) {
    __builtin_amdgcn_global_load_lds((gas1_t)g, (las3_t)l, 16, 0, 0);
}

// ---------------------------------------------------------------------------
// Prep. Blocks 0..63: embed -> B-frag-tiled bf16 hi/lo + nhcc.
//       Blocks 64..95: W -> flat bf16 hi/lo.
// Tiled layout per 128-k chunk (8192 shorts/plane): slot for (r=k&127, e):
//   kt=r>>4, col=r&15, ks=e>>5, qe=(e>>3)&3 -> ((kt*2+ks)*64 + qe*16 + col)*8 + (e&7)
// so a vq wave's B-frag read (pb + lane*8) is a coalesced 1 KB run directly
// from global (L2-resident).
// ---------------------------------------------------------------------------
__global__ void prep_kernel(const float* __restrict__ embed,
                            const float* __restrict__ W,
                            short* __restrict__ ehi, short* __restrict__ elo,
                            float* __restrict__ nhcc,
                            short* __restrict__ whi, short* __restrict__ wlo) {
    const int tid = threadIdx.x;
    if (blockIdx.x < 64) {
        const int row = blockIdx.x * 32 + (tid >> 3);
        const int g = tid & 7;
        const float* src = embed + (size_t)row * 64 + g * 8;
        short8 hv, lv;
        float s = 0.f;
#pragma unroll
        for (int j = 0; j < 8; ++j) {
            float v = src[j];
            s = fmaf(v, v, s);
            HiLo r = split_rne(v);
            hv[j] = r.hi; lv[j] = r.lo;
        }
        const int c128 = row >> 7, r = row & 127;
        const int kt = r >> 4, col = r & 15, ks = g >> 2, qe = g & 3;
        const int slot = (kt * 2 + ks) * 64 + qe * 16 + col;
        *(short8*)(ehi + c128 * 8192 + slot * 8) = hv;
        *(short8*)(elo + c128 * 8192 + slot * 8) = lv;
        s += __shfl_xor(s, 1, 64);
        s += __shfl_xor(s, 2, 64);
        s += __shfl_xor(s, 4, 64);
        if (g == 0) nhcc[row] = -0.5f * s;
    } else {
        int idx = ((blockIdx.x - 64) * 256 + tid) * 4;
        float4 v = *(const float4*)(W + idx);
        short4v h, l;
        HiLo a = split_rne(v.x); h[0] = a.hi; l[0] = a.lo;
        HiLo b = split_rne(v.y); h[1] = b.hi; l[1] = b.lo;
        HiLo c = split_rne(v.z); h[2] = c.hi; l[2] = c.lo;
        HiLo d = split_rne(v.w); h[3] = d.hi; l[3] = d.lo;
        *(short4v*)(whi + idx) = h;
        *(short4v*)(wlo + idx) = l;
    }
}

// ---------------------------------------------------------------------------
// proj_kernel v3: wave owns 64 t. x loaded as lane-float4 (256-B contiguous
// segments per c-row, 4x the old granule -> 4x bytes per in-flight miss),
// transposed through WAVE-PRIVATE LDS (no barriers; DS is in-order per wave).
// Per iteration (32 c): 8 x 1KB global loads -> private LDS [32][66] ->
// B-frags via 2-way-conflict-free b32 reads -> 64 MFMA.
// Block 256 thr (4 waves x 64 t = 256 t). Grid 256.
// ---------------------------------------------------------------------------
__global__ __launch_bounds__(256, 2) void proj_kernel(
        const float* __restrict__ x,
        const short* __restrict__ whi, const short* __restrict__ wlo,
        const float* __restrict__ bias,
        short* __restrict__ himg, float* __restrict__ lossacc) {
    __shared__ __align__(16) float xw[4 * 32 * 66];   // 33792 B, wave-private slices

    const int tid = threadIdx.x;
    const int wave = tid >> 6, lane = tid & 63;
    const int row16 = lane & 15, quad = lane >> 4;
    const int blk = blockIdx.x;            // 256 blocks, 256 t each
    const int b  = blk >> 4;
    const int t0 = (blk & 15) * 256;
    const int t0w = t0 + wave * 64;
    const float* xr = x + (size_t)b * C_ * T_ + t0w;
    float* wl = xw + wave * (32 * 66);

    const int c_row = lane >> 4;           // 0..3 (row within 4-row load group)
    const int c_t4  = (lane & 15) * 4;     // t offset (16 lanes x float4 = 256 B)

    f32x4 acc[4][4];
#pragma unroll
    for (int rt = 0; rt < 4; ++rt)
#pragma unroll
        for (int et = 0; et < 4; ++et) acc[rt][et] = (f32x4){0.f, 0.f, 0.f, 0.f};

    float4 xn[8];
#pragma unroll
    for (int q = 0; q < 8; ++q)
        xn[q] = *(const float4*)(xr + (size_t)(q * 4 + c_row) * T_ + c_t4);

    for (int it = 0; it < 16; ++it) {
        const int c0 = it * 32;
        // park chunk `it` into private LDS (b64 pairs; rows 8-B aligned)
#pragma unroll
        for (int q = 0; q < 8; ++q) {
            float* d = wl + (q * 4 + c_row) * 66 + c_t4;
            *(float2*)(d)     = make_float2(xn[q].x, xn[q].y);
            *(float2*)(d + 2) = make_float2(xn[q].z, xn[q].w);
        }
        // prefetch chunk it+1 (full iteration of compute to hide latency)
        if (it < 15) {
#pragma unroll
            for (int q = 0; q < 8; ++q)
                xn[q] = *(const float4*)(xr + (size_t)(c0 + 32 + q * 4 + c_row) * T_ + c_t4);
        }
        // compute: two rt-pairs, frags read transposed from private LDS
#pragma unroll
        for (int rp = 0; rp < 2; ++rp) {
            short8 bh[2], bl[2];
#pragma unroll
            for (int rr = 0; rr < 2; ++rr) {
                const int rt = rp * 2 + rr;
#pragma unroll
                for (int j = 0; j < 8; ++j) {
                    float v = wl[(quad * 8 + j) * 66 + rt * 16 + row16];
                    HiLo r = split_rne(v);
                    bh[rr][j] = r.hi; bl[rr][j] = r.lo;
                }
            }
#pragma unroll
            for (int et = 0; et < 4; ++et) {
                size_t aoff = (size_t)(et * 16 + row16) * C_ + c0 + quad * 8;
                short8 ah = *(const short8*)(whi + aoff);
                short8 al = *(const short8*)(wlo + aoff);
#pragma unroll
                for (int rr = 0; rr < 2; ++rr) {
                    const int rt = rp * 2 + rr;
                    acc[rt][et] = __builtin_amdgcn_mfma_f32_16x16x32_bf16(ah, bh[rr], acc[rt][et], 0, 0, 0);
                    acc[rt][et] = __builtin_amdgcn_mfma_f32_16x16x32_bf16(al, bh[rr], acc[rt][et], 0, 0, 0);
                    acc[rt][et] = __builtin_amdgcn_mfma_f32_16x16x32_bf16(ah, bl[rr], acc[rt][et], 0, 0, 0);
                    acc[rt][et] = __builtin_amdgcn_mfma_f32_16x16x32_bf16(al, bl[rr], acc[rt][et], 0, 0, 0);
                }
            }
        }
    }

    // Epilogue: bias, ||h||^2, store h hi/lo in A-frag order to himg.
    // tile16 = wave*4 + rt (16-row t-tile within the block's 256 t);
    // himg group g = blk*2 + (tile16>>3), w2 = tile16&7.
    float hh = 0.f;
#pragma unroll
    for (int rt = 0; rt < 4; ++rt) {
        const int tile16 = wave * 4 + rt;
        short* gb = himg + (size_t)(blk * 2 + (tile16 >> 3)) * 16384;
        const int w2 = tile16 & 7;
#pragma unroll
        for (int et = 0; et < 4; ++et) {
            float4 bv = *(const float4*)(bias + et * 16 + quad * 4);
            f32x4 a = acc[rt][et];
            a[0] += bv.x; a[1] += bv.y; a[2] += bv.z; a[3] += bv.w;
            hh = fmaf(a[0], a[0], hh); hh = fmaf(a[1], a[1], hh);
            hh = fmaf(a[2], a[2], hh); hh = fmaf(a[3], a[3], hh);
            short4v hv, lv;
#pragma unroll
            for (int r = 0; r < 4; ++r) {
                HiLo sp = split_rne(a[r]);
                hv[r] = sp.hi; lv[r] = sp.lo;
            }
            const int ks = et >> 1;
            const int qe = (et & 1) * 2 + (quad >> 1);
            const int j0 = (quad & 1) * 4;
            const int sl = ((w2 * 2 + ks) * 64 + qe * 16 + row16) * 8 + j0;
            *(short4v*)(gb + sl) = hv;
            *(short4v*)(gb + 8192 + sl) = lv;
        }
    }
#pragma unroll
    for (int m = 1; m < 64; m <<= 1) hh += __shfl_xor(hh, m, 64);
    if (lane == 0) atomicAdd(lossacc, hh);
}

// ---------------------------------------------------------------------------
// vq_kernel v3: wave covers 64 rows (rt=4) with kh-split -> each 4-load
// (4 KB) group feeds 24 MFMAs (1:6 load:MFMA, half the L2 traffic).
// Explicit double-buffered B prefetch (static parity). Block 256 thr =
// {2 rowgrps x 2 kh} = 128 rows. Grid 512.
// ---------------------------------------------------------------------------
#define VQ_STEP(H0, H1, L0, L1, SS)                                            \
    {                                                                          \
        const int kk = ((SS) >> 2) * 128 + (kh * 4 + ((SS) & 3)) * 16 + row16; \
        const float ci = nhcc[kk];                                             \
        _Pragma("unroll")                                                      \
        for (int rt = 0; rt < 4; ++rt) {                                       \
            f32x4 a2 = (f32x4){0.f, 0.f, 0.f, 0.f};                            \
            a2 = __builtin_amdgcn_mfma_f32_16x16x32_bf16(a_hi[rt][0], H0, a2, 0, 0, 0); \
            a2 = __builtin_amdgcn_mfma_f32_16x16x32_bf16(a_hi[rt][1], H1, a2, 0, 0, 0); \
            a2 = __builtin_amdgcn_mfma_f32_16x16x32_bf16(a_lo[rt][0], H0, a2, 0, 0, 0); \
            a2 = __builtin_amdgcn_mfma_f32_16x16x32_bf16(a_lo[rt][1], H1, a2, 0, 0, 0); \
            a2 = __builtin_amdgcn_mfma_f32_16x16x32_bf16(a_hi[rt][0], L0, a2, 0, 0, 0); \
            a2 = __builtin_amdgcn_mfma_f32_16x16x32_bf16(a_hi[rt][1], L1, a2, 0, 0, 0); \
            _Pragma("unroll")                                                  \
            for (int rg = 0; rg < 4; ++rg) {                                   \
                float v = a2[rg] + ci;                                         \
                if (v > vmax[rt][rg]) { vmax[rt][rg] = v; vidx[rt][rg] = kk; } \
            }                                                                  \
        }                                                                      \
    }

#define VQ_LOAD(H0, H1, L0, L1, SS)                                            \
    {                                                                          \
        const int c2 = (SS) >> 2, kt2 = kh * 4 + ((SS) & 3);                   \
        const short* pb = ehi + c2 * 8192 + kt2 * 1024;                        \
        const short* pl = elo + c2 * 8192 + kt2 * 1024;                        \
        H0 = *(const short8*)(pb + lane * 8);                                  \
        H1 = *(const short8*)(pb + 512 + lane * 8);                            \
        L0 = *(const short8*)(pl + lane * 8);                                  \
        L1 = *(const short8*)(pl + 512 + lane * 8);                            \
    }

__global__ __launch_bounds__(256, 2) void vq_kernel(
        const short* __restrict__ himg,
        const short* __restrict__ ehi, const short* __restrict__ elo,
        const float* __restrict__ nhcc,
        const float* __restrict__ embed, float* __restrict__ out,
        int* __restrict__ hist, float* __restrict__ lossacc) {
    __shared__ __align__(16) float tile[128 * 69];   // 35328 B (gather)
    __shared__ int   qsm[128];
    __shared__ float vtmp[128];
    __shared__ int   itmp[128];

    const int tid = threadIdx.x;
    const int wave = tid >> 6, lane = tid & 63;
    const int row16 = lane & 15, quad = lane >> 4;
    const int g = blockIdx.x;
    const int b  = g >> 5;
    const int t0 = (g & 31) * 128;
    const int rowgrp = wave & 1, kh = wave >> 1;

    // A-frags: lane-linear from global h-image (4 rt x 2 ks, hi+lo).
    const short* gb = himg + (size_t)g * 16384;
    short8 a_hi[4][2], a_lo[4][2];
#pragma unroll
    for (int rt = 0; rt < 4; ++rt)
#pragma unroll
        for (int ks = 0; ks < 2; ++ks) {
            const int w2 = rowgrp * 4 + rt;
            const int sl = ((w2 * 2 + ks) * 64 + lane) * 8;
            a_hi[rt][ks] = *(const short8*)(gb + sl);
            a_lo[rt][ks] = *(const short8*)(gb + 8192 + sl);
        }

    float vmax[4][4];
    int   vidx[4][4];
#pragma unroll
    for (int rt = 0; rt < 4; ++rt)
#pragma unroll
        for (int rg = 0; rg < 4; ++rg) { vmax[rt][rg] = -3.4e38f; vidx[rt][rg] = 0; }

    short8 pAh0, pAh1, pAl0, pAl1;
    short8 pBh0, pBh1, pBl0, pBl1;
    VQ_LOAD(pAh0, pAh1, pAl0, pAl1, 0);
    for (int s = 0; s < 64; s += 2) {
        VQ_LOAD(pBh0, pBh1, pBl0, pBl1, s + 1);
        VQ_STEP(pAh0, pAh1, pAl0, pAl1, s);
        if (s + 2 < 64) VQ_LOAD(pAh0, pAh1, pAl0, pAl1, s + 2);
        VQ_STEP(pBh0, pBh1, pBl0, pBl1, s + 1);
    }

    // 16-lane k-reduce (tie -> lowest idx), then merge kh halves via LDS.
    float s_loss = 0.f;
#pragma unroll
    for (int rt = 0; rt < 4; ++rt)
#pragma unroll
        for (int rg = 0; rg < 4; ++rg) {
            float v = vmax[rt][rg];
            int ix = vidx[rt][rg];
#pragma unroll
            for (int m = 1; m < 16; m <<= 1) {
                float ov = __shfl_xor(v, m, 64);
                int   oi = __shfl_xor(ix, m, 64);
                if (ov > v || (ov == v && oi < ix)) { v = ov; ix = oi; }
            }
            vmax[rt][rg] = v; vidx[rt][rg] = ix;
        }
    if (kh == 1 && row16 == 0) {
#pragma unroll
        for (int rt = 0; rt < 4; ++rt)
#pragma unroll
            for (int rg = 0; rg < 4; ++rg) {
                const int row = (rowgrp * 4 + rt) * 16 + quad * 4 + rg;
                vtmp[row] = vmax[rt][rg];
                itmp[row] = vidx[rt][rg];
            }
    }
    __syncthreads();
    if (kh == 0) {
        if (row16 == 0) {
#pragma unroll
            for (int rt = 0; rt < 4; ++rt)
#pragma unroll
                for (int rg = 0; rg < 4; ++rg) {
                    const int row = (rowgrp * 4 + rt) * 16 + quad * 4 + rg;
                    float v = vmax[rt][rg];
                    int ix = vidx[rt][rg];
                    const float ov = vtmp[row];
                    const int   oi = itmp[row];
                    if (ov > v || (ov == v && oi < ix)) { v = ov; ix = oi; }
                    qsm[row] = ix;
                    atomicAdd(&hist[ix], 1);
                    s_loss += v;
                }
        }
        s_loss += __shfl_xor(s_loss, 16, 64);
        s_loss += __shfl_xor(s_loss, 32, 64);
        if (lane == 0) atomicAdd(lossacc, -2.f * s_loss);
    }
    __syncthreads();

    // ---------------- Fused gather + transpose (256-thr) ----------------
    {
        const int r = tid >> 1, piece = tid & 1;
        const float* src = embed + (size_t)qsm[r] * 64 + piece * 32;
        float* dst = tile + r * 69 + piece * 32;
#pragma unroll
        for (int j = 0; j < 8; ++j)
            *(float4*)(dst + j * 4) = *(const float4*)(src + j * 4);
    }
    __syncthreads();
    {
        const int tt = tid & 63;
        const int eo = tid >> 6;               // 0..3
        float* ob = out + ((size_t)b * 64) * T_ + t0;
#pragma unroll
        for (int j = 0; j < 16; ++j) {
            const int e = j * 4 + eo;
            ob[(size_t)e * T_ + tt]      = tile[tt * 69 + e];
            ob[(size_t)e * T_ + 64 + tt] = tile[(tt + 64) * 69 + e];
        }
    }
}

// ---------------------------------------------------------------------------
// Fused fallback (verified round-1 kernel) — used only if ws is too small
// for the h-image.
// ---------------------------------------------------------------------------
__global__ __launch_bounds__(512, 4) void projvq_kernel(
        const float* __restrict__ x,
        const short* __restrict__ whi, const short* __restrict__ wlo,
        const float* __restrict__ bias,
        const short* __restrict__ ehi, const short* __restrict__ elo,
        const float* __restrict__ nhcc,
        const float* __restrict__ embed, float* __restrict__ out,
        int* __restrict__ hist, float* __restrict__ lossacc) {
    __shared__ __align__(16) char smem[68096];
    float* xsf  = (float*)smem;
    short* es   = (short*)smem;
    short* aimg = (short*)(smem + 32768);
    float* ccs  = (float*)(smem + 65536);
    int*   qsm2 = (int*)(smem + 66560);
    float* vtmp = (float*)(smem + 67072);
    int*   itmp = (int*)(smem + 67584);
    float* tile = (float*)smem;

    const int tid = threadIdx.x;
    const int wave = tid >> 6, lane = tid & 63;
    const int row16 = lane & 15, quad = lane >> 4;
    const int b  = blockIdx.x >> 5;
    const int t0 = (blockIdx.x & 31) * 128;
    const float* xb = x + (size_t)b * C_ * T_ + t0;

    f32x4 cc = *(const f32x4*)(nhcc + tid * 4);

    f32x4 acc[4];
#pragma unroll
    for (int et = 0; et < 4; ++et) acc[et] = (f32x4){0.f, 0.f, 0.f, 0.f};

#pragma unroll
    for (int j = 0; j < 2; ++j) {
        int o = j * 512 + tid;
        gl16(xb + (size_t)(o >> 5) * T_ + (o & 31) * 4, xsf + o * 4);
    }
    __syncthreads();

    for (int it = 0; it < 16; ++it) {
        const int c0 = it * 32;
        const int p = it & 1;
        if (it < 15) {
#pragma unroll
            for (int j = 0; j < 2; ++j) {
                int o = j * 512 + tid;
                gl16(xb + (size_t)(c0 + 32 + (o >> 5)) * T_ + (o & 31) * 4,
                     xsf + (p ^ 1) * 4096 + o * 4);
            }
        }
        const float* xsb = xsf + p * 4096;
        short8 bh, bl;
#pragma unroll
        for (int j = 0; j < 8; ++j) {
            float v = xsb[(quad * 8 + j) * 128 + wave * 16 + row16];
            HiLo r = split_rne(v);
            bh[j] = r.hi; bl[j] = r.lo;
        }
#pragma unroll
        for (int et = 0; et < 4; ++et) {
            size_t aoff = (size_t)(et * 16 + row16) * C_ + c0 + quad * 8;
            short8 ah = *(const short8*)(whi + aoff);
            short8 al = *(const short8*)(wlo + aoff);
            acc[et] = __builtin_amdgcn_mfma_f32_16x16x32_bf16(ah, bh, acc[et], 0, 0, 0);
            acc[et] = __builtin_amdgcn_mfma_f32_16x16x32_bf16(al, bh, acc[et], 0, 0, 0);
            acc[et] = __builtin_amdgcn_mfma_f32_16x16x32_bf16(ah, bl, acc[et], 0, 0, 0);
            acc[et] = __builtin_amdgcn_mfma_f32_16x16x32_bf16(al, bl, acc[et], 0, 0, 0);
        }
        __syncthreads();
    }

#pragma unroll
    for (int j = 0; j < 2; ++j) {
        int o = (j * 512 + tid) * 8;
        gl16(ehi + o, es + o);
        gl16(elo + o, es + 8192 + o);
    }

    float hh = 0.f;
#pragma unroll
    for (int et = 0; et < 4; ++et) {
        float4 bv = *(const float4*)(bias + et * 16 + quad * 4);
        f32x4 a = acc[et];
        a[0] += bv.x; a[1] += bv.y; a[2] += bv.z; a[3] += bv.w;
        hh = fmaf(a[0], a[0], hh); hh = fmaf(a[1], a[1], hh);
        hh = fmaf(a[2], a[2], hh); hh = fmaf(a[3], a[3], hh);
        short4v hv, lv;
#pragma unroll
        for (int r = 0; r < 4; ++r) {
            HiLo sp = split_rne(a[r]);
            hv[r] = sp.hi; lv[r] = sp.lo;
        }
        const int ks = et >> 1;
        const int qe = (et & 1) * 2 + (quad >> 1);
        const int j0 = (quad & 1) * 4;
        const int sl = ((wave * 2 + ks) * 64 + qe * 16 + row16) * 8 + j0;
        *(short4v*)(aimg + sl) = hv;
        *(short4v*)(aimg + 8192 + sl) = lv;
    }
#pragma unroll
    for (int m = 1; m < 64; m <<= 1) hh += __shfl_xor(hh, m, 64);
    if (lane == 0) atomicAdd(lossacc, hh);
    __syncthreads();

    const int pair = wave & 3, kh = wave >> 2;
    short8 a_hi[2][2], a_lo[2][2];
#pragma unroll
    for (int rt = 0; rt < 2; ++rt)
#pragma unroll
        for (int ks = 0; ks < 2; ++ks) {
            int sl = (((2 * pair + rt) * 2 + ks) * 64 + lane) * 8;
            a_hi[rt][ks] = *(const short8*)(aimg + sl);
            a_lo[rt][ks] = *(const short8*)(aimg + 8192 + sl);
        }
    if ((tid >> 5) == 0) *(f32x4*)(ccs + (tid & 31) * 4) = cc;
    __syncthreads();

    float vmax[2][4];
    int   vidx[2][4];
#pragma unroll
    for (int rt = 0; rt < 2; ++rt)
#pragma unroll
        for (int rg = 0; rg < 4; ++rg) { vmax[rt][rg] = -3.4e38f; vidx[rt][rg] = 0; }

    for (int c = 0; c < 16; ++c) {
        if (c < 15) {
            const short* sh  = ehi + (c + 1) * 8192;
            const short* sl2 = elo + (c + 1) * 8192;
            short* dst = es + ((c + 1) & 1) * 16384;
#pragma unroll
            for (int j = 0; j < 2; ++j) {
                int o = (j * 512 + tid) * 8;
                gl16(sh + o, dst + o);
                gl16(sl2 + o, dst + 8192 + o);
            }
            if ((tid >> 5) == c + 1)
                *(f32x4*)(ccs + ((c + 1) & 1) * 128 + (tid & 31) * 4) = cc;
        }
        const short* eb = es + (c & 1) * 16384;
        const float* cb = ccs + (c & 1) * 128;
#pragma unroll
        for (int k4 = 0; k4 < 4; ++k4) {
            const int kt = kh * 4 + k4;
            const float ci = cb[kt * 16 + row16];
            const short* pb = eb + kt * 1024;
            short8 bh0 = *(const short8*)(pb + lane * 8);
            short8 bh1 = *(const short8*)(pb + 512 + lane * 8);
            short8 bl0 = *(const short8*)(pb + 8192 + lane * 8);
            short8 bl1 = *(const short8*)(pb + 8192 + 512 + lane * 8);
            const int kk = c * 128 + kt * 16 + row16;
#pragma unroll
            for (int rt = 0; rt < 2; ++rt) {
                f32x4 a2 = (f32x4){0.f, 0.f, 0.f, 0.f};
                a2 = __builtin_amdgcn_mfma_f32_16x16x32_bf16(a_hi[rt][0], bh0, a2, 0, 0, 0);
                a2 = __builtin_amdgcn_mfma_f32_16x16x32_bf16(a_hi[rt][1], bh1, a2, 0, 0, 0);
                a2 = __builtin_amdgcn_mfma_f32_16x16x32_bf16(a_lo[rt][0], bh0, a2, 0, 0, 0);
                a2 = __builtin_amdgcn_mfma_f32_16x16x32_bf16(a_lo[rt][1], bh1, a2, 0, 0, 0);
                a2 = __builtin_amdgcn_mfma_f32_16x16x32_bf16(a_hi[rt][0], bl0, a2, 0, 0, 0);
                a2 = __builtin_amdgcn_mfma_f32_16x16x32_bf16(a_hi[rt][1], bl1, a2, 0, 0, 0);
#pragma unroll
                for (int rg = 0; rg < 4; ++rg) {
                    float v = a2[rg] + ci;
                    if (v > vmax[rt][rg]) { vmax[rt][rg] = v; vidx[rt][rg] = kk; }
                }
            }
        }
        __syncthreads();
    }

    float s = 0.f;
#pragma unroll
    for (int rt = 0; rt < 2; ++rt)
#pragma unroll
        for (int rg = 0; rg < 4; ++rg) {
            float v = vmax[rt][rg];
            int ix = vidx[rt][rg];
#pragma unroll
            for (int m = 1; m < 16; m <<= 1) {
                float ov = __shfl_xor(v, m, 64);
                int   oi = __shfl_xor(ix, m, 64);
                if (ov > v || (ov == v && oi < ix)) { v = ov; ix = oi; }
            }
            vmax[rt][rg] = v; vidx[rt][rg] = ix;
        }
    if (kh == 1 && row16 == 0) {
#pragma unroll
        for (int rt = 0; rt < 2; ++rt)
#pragma unroll
            for (int rg = 0; rg < 4; ++rg) {
                const int row = (2 * pair + rt) * 16 + quad * 4 + rg;
                vtmp[row] = vmax[rt][rg];
                itmp[row] = vidx[rt][rg];
            }
    }
    __syncthreads();
    if (kh == 0) {
        if (row16 == 0) {
#pragma unroll
            for (int rt = 0; rt < 2; ++rt)
#pragma unroll
                for (int rg = 0; rg < 4; ++rg) {
                    const int row = (2 * pair + rt) * 16 + quad * 4 + rg;
                    float v = vmax[rt][rg];
                    int ix = vidx[rt][rg];
                    const float ov = vtmp[row];
                    const int   oi = itmp[row];
                    if (ov > v || (ov == v && oi < ix)) { v = ov; ix = oi; }
                    qsm2[row] = ix;
                    atomicAdd(&hist[ix], 1);
                    s += v;
                }
        }
        s += __shfl_xor(s, 16, 64);
        s += __shfl_xor(s, 32, 64);
        if (lane == 0) atomicAdd(lossacc, -2.f * s);
    }
    __syncthreads();

    {
        const int r = tid >> 2, piece = tid & 3;
        const float* src = embed + (size_t)qsm2[r] * 64 + piece * 16;
        float* dst = tile + r * 69 + piece * 16;
#pragma unroll
        for (int j = 0; j < 4; ++j)
            *(float4*)(dst + j * 4) = *(const float4*)(src + j * 4);
    }
    __syncthreads();
    {
        const int tt = tid & 63;
        const int eo = tid >> 6;
#pragma unroll
        for (int j = 0; j < 8; ++j) {
            const int e = j * 8 + eo;
            float* ob = out + ((size_t)b * 64) * T_ + t0;
            ob[(size_t)e * T_ + tt]      = tile[tt * 69 + e];
            ob[(size_t)e * T_ + 64 + tt] = tile[(tt + 64) * 69 + e];
        }
    }
}

// ---------------------------------------------------------------------------
// Finalize: loss, kldiv constant, log-perplexity.
// ---------------------------------------------------------------------------
__global__ void finalize_kernel(const int* __restrict__ hist,
                                const float* __restrict__ lossacc,
                                float* __restrict__ out) {
    __shared__ float red[4];
    const int tid = threadIdx.x;
    float s = 0.f;
    for (int k = tid; k < K_; k += 256) {
        float p = (float)hist[k] * (1.f / 65536.f);
        s -= p * logf(p + 1e-10f);
    }
#pragma unroll
    for (int m = 1; m < 64; m <<= 1) s += __shfl_xor(s, m, 64);
    if ((tid & 63) == 0) red[tid >> 6] = s;
    __syncthreads();
    if (tid == 0) {
        float lp = red[0] + red[1] + red[2] + red[3];
        out[ZQ_ELEMS] = 0.25f * lossacc[0] / (float)ZQ_ELEMS;    // loss
        out[ZQ_ELEMS + 17] = lp;                                  // log_perplexity
    }
    if (tid < 16) out[ZQ_ELEMS + 1 + tid] = logf(2048.f) * 4096.f;  // kldiv_r
}

// ---------------------------------------------------------------------------
extern "C" void kernel_launch(void* const* d_in, const int* in_sizes, int n_in,
                              void* d_out, int out_size, void* d_ws, size_t ws_size,
                              hipStream_t stream) {
    const float* x      = (const float*)d_in[0];
    const float* proj_w = (const float*)d_in[1];
    const float* proj_b = (const float*)d_in[2];
    const float* embed  = (const float*)d_in[3];
    float* out = (float*)d_out;
    char* ws = (char*)d_ws;

    short* e_hi = (short*)(ws + WS_EHI);
    short* e_lo = (short*)(ws + WS_ELO);
    float* nhcc = (float*)(ws + WS_NHCC);
    short* w_hi = (short*)(ws + WS_WHI);
    short* w_lo = (short*)(ws + WS_WLO);
    int*   hist = (int*)(ws + WS_HIST);
    float* lossac = (float*)(ws + WS_LOSS);
    short* himg = (short*)(ws + WS_HIMG);

    // hist + loss adjacent; zero both (ws poisoned 0xAA each launch).
    (void)hipMemsetAsync(ws + WS_HIST, 0, K_ * sizeof(int) + sizeof(float), stream);

    prep_kernel<<<96, 256, 0, stream>>>(embed, proj_w, e_hi, e_lo, nhcc, w_hi, w_lo);
    if (ws_size >= (size_t)WS_NEED) {
        proj_kernel<<<256, 256, 0, stream>>>(x, w_hi, w_lo, proj_b, himg, lossac);
        vq_kernel<<<512, 256, 0, stream>>>(himg, e_hi, e_lo, nhcc, embed, out,
                                           hist, lossac);
    } else {
        projvq_kernel<<<N_ / 128, 512, 0, stream>>>(x, w_hi, w_lo, proj_b,
                                                    e_hi, e_lo, nhcc, embed, out,
                                                    hist, lossac);
    }
    finalize_kernel<<<1, 256, 0, stream>>>(hist, lossac, out);
}